// Round 10
// baseline (45.958 us; speedup 1.0000x reference)
//
#include <hip/hip_runtime.h>
#include <math.h>

#define Bn 16
#define Ln 1444      // 38*38
#define NCn 21
#define Cn 64
#define NBn 23       // 64-position tiles
#define KC 1344      // 21*64
#define NG 336       // KC/4 float4 groups

// ---- Kernel B: classify (LDS-staged) + transpose + per-block class sums ---
// (R6 version, measured ~7 us)
__global__ __launch_bounds__(256) void kB(const float* __restrict__ cls_pred,
                                          const float* __restrict__ source,
                                          int* __restrict__ cls_idx,
                                          float* __restrict__ src_out,
                                          float* __restrict__ bs) {
    int b = blockIdx.x / NBn, m = blockIdx.x % NBn;
    int base = m * 64;
    int lane = threadIdx.x & 63, grp = threadIdx.x >> 6;
    __shared__ float sh[9536];
    __shared__ int cls[64];
    float (*tile)[65] = (float(*)[65])sh;   // [64][65]
    float* clsP = sh + 4160;                // 5376 floats, dead after classify
    float* WS   = sh + 4160;                // [4][1344] overlays clsP

#pragma unroll
    for (int cc = 0; cc < 16; cc++) {
        int c = grp * 16 + cc;
        float v = 0.f;
        if (base + lane < Ln) v = source[((size_t)b * Cn + c) * Ln + base + lane];
        tile[c][lane] = v;
    }
    {
        const float4* gp = reinterpret_cast<const float4*>(cls_pred + ((size_t)b * Ln + base) * 84);
        int lim4 = (Ln - base) * 21;
#pragma unroll
        for (int it = 0; it < 6; it++) {
            int f4 = threadIdx.x + it * 256;
            if (f4 < 1344) {
                float4 v = (f4 < lim4) ? gp[f4] : make_float4(0.f, 0.f, 0.f, 0.f);
                reinterpret_cast<float4*>(clsP)[f4] = v;
            }
        }
    }
    __syncthreads();   // S1

    {
        int p = threadIdx.x >> 2, a = threadIdx.x & 3;
        bool valid = (base + p < Ln);
        const float* q = clsP + p * 84 + a * 21;
        float x[21];
#pragma unroll
        for (int i = 0; i < 21; i++) x[i] = q[i];
        float mx = x[0];
#pragma unroll
        for (int i = 1; i < 21; i++) mx = fmaxf(mx, x[i]);
        float s = 0.f;
#pragma unroll
        for (int i = 0; i < 21; i++) { x[i] = expf(x[i] - mx); s += x[i]; }
        float best = -1.f; int bi = 0;
#pragma unroll
        for (int i = 0; i < 21; i++) {
            float sm = x[i] / s;                     // exact per-element division (matches ref)
            if (sm > best) { best = sm; bi = a * 21 + i; }
        }
#pragma unroll
        for (int d = 1; d <= 2; d <<= 1) {
            float ob = __shfl_xor(best, d);
            int oi = __shfl_xor(bi, d);
            if (ob > best || (ob == best && oi < bi)) { best = ob; bi = oi; }
        }
        if (a == 0) {
            if (valid) { int k = bi % 21; cls[p] = k; cls_idx[b * Ln + base + p] = k; }
            else cls[p] = 255;
        }
    }
    __syncthreads();   // S2: cls ready, clsP dead

    float cs[21];
#pragma unroll
    for (int k = 0; k < 21; k++) cs[k] = 0.f;
#pragma unroll
    for (int jj = 0; jj < 16; jj++) {
        int j = grp * 16 + jj;
        float v = tile[lane][j];                 // stride-65: conflict-free
        if (base + j < Ln) src_out[((size_t)b * Ln + base + j) * Cn + lane] = v;
        int k = cls[j];                          // wave-uniform broadcast
#pragma unroll
        for (int kk = 0; kk < 21; kk++) cs[kk] += (kk == k) ? v : 0.f;
    }
#pragma unroll
    for (int kk = 0; kk < 21; kk++) WS[grp * KC + kk * 64 + lane] = cs[kk];
    __syncthreads();   // S3

    for (int i = threadIdx.x; i < KC; i += 256) {
        float v = WS[i] + WS[KC + i] + WS[2 * KC + i] + WS[3 * KC + i];
        bs[((size_t)b * NBn + m) * KC + i] = v;
    }
}

// ---- Kernel C: ds_add class sums + wave-constant msW + triangular ---------
// LDS: PS 5.4K + Tt 5.4K + WS[8] 43K + Q 3.5K + cls 256B  (~57.7 KB, 2 blk/CU)
__global__ __launch_bounds__(512) void kC(const float* __restrict__ src,
                                          const int* __restrict__ cls_idx,
                                          const float* __restrict__ R,
                                          const float* __restrict__ bs,
                                          float* __restrict__ fused) {
    int b = blockIdx.x / NBn, m = blockIdx.x % NBn;
    int base = m * 64;
    int lane = threadIdx.x & 63, grp = threadIdx.x >> 6;   // 8 waves, 8 pos each
    __shared__ float PS[KC];
    __shared__ float Tt[KC];
    __shared__ float WS[8][KC];    // per-wave class sums -> exclusive prefix in-place
    __shared__ float2 Q[441];      // (R[a][k]-R[k][a], R[k][a])
    __shared__ int cls[64];

    // own 8 positions into registers (coalesced rows, independent loads)
    float sT[8];
#pragma unroll
    for (int t = 0; t < 8; t++) {
        int i = grp * 8 + t;
        sT[t] = (base + i < Ln) ? src[((size_t)b * Ln + base + i) * Cn + lane] : 0.f;
    }
    // bs stream: 336 threads, 3 batched rounds of 8/8/7 in-flight loads
    if (threadIdx.x < NG) {
        const float4* pp = reinterpret_cast<const float4*>(bs) + (size_t)b * NBn * NG + threadIdx.x;
        float rx = 0.f, ry = 0.f, rz = 0.f, rw = 0.f;
        float px = 0.f, py = 0.f, pz = 0.f, pw = 0.f;
        float4 v[8];
#pragma unroll
        for (int r = 0; r < 3; r++) {
            int mm0 = r * 8, cnt = (r == 2) ? 7 : 8;
#pragma unroll
            for (int j = 0; j < 8; j++)
                if (j < cnt) v[j] = pp[(size_t)(mm0 + j) * NG];
#pragma unroll
            for (int j = 0; j < 8; j++)
                if (j < cnt) {
                    rx += v[j].x; ry += v[j].y; rz += v[j].z; rw += v[j].w;
                    if (mm0 + j < m) { px += v[j].x; py += v[j].y; pz += v[j].z; pw += v[j].w; }
                }
        }
        int g = threadIdx.x;
        PS[g * 4] = px; PS[g * 4 + 1] = py; PS[g * 4 + 2] = pz; PS[g * 4 + 3] = pw;
        Tt[g * 4] = rx; Tt[g * 4 + 1] = ry; Tt[g * 4 + 2] = rz; Tt[g * 4 + 3] = rw;
    }
    if (threadIdx.x < 64) {
        int k = 255;
        if (base + (int)threadIdx.x < Ln) k = cls_idx[b * Ln + base + threadIdx.x];
        cls[threadIdx.x] = k;
    }
    if (threadIdx.x < 441) {
        int a = threadIdx.x / 21, k = threadIdx.x % 21;
        float rak = R[a * 21 + k], rka = R[k * 21 + a];
        Q[threadIdx.x] = make_float2(rak - rka, rka);
    }
    // zero WS
    {
        float* f = &WS[0][0];
        for (int i = threadIdx.x; i < 8 * KC; i += 512) f[i] = 0.f;
    }
    __syncthreads();   // S1: PS/Tt/Q/cls ready, WS zeroed

    // per-wave class sums via LDS float atomics (fire-and-forget ds_add)
#pragma unroll
    for (int t = 0; t < 8; t++) {
        int k = cls[grp * 8 + t];
        if (k < 21) atomicAdd(&WS[grp][k * 64 + lane], sT[t]);
    }
    __syncthreads();   // S2: WS rows complete

    // cooperative exclusive prefix over the 8 wave rows, seeded with PS
    for (int i = threadIdx.x; i < KC; i += 512) {
        float run = PS[i];
#pragma unroll
        for (int g = 0; g < 8; g++) {
            float w = WS[g][i];
            WS[g][i] = run;
            run += w;
        }
    }
    __syncthreads();   // S3: WS[g] = class-prefix before wave g's first position

    // registers: totals column, own wave's msW, own wave's classes
    float Tc[21], msW[21];
#pragma unroll
    for (int k = 0; k < 21; k++) Tc[k] = Tt[k * 64 + lane];
#pragma unroll
    for (int k = 0; k < 21; k++) msW[k] = WS[grp][k * 64 + lane];
    int cj[8];
#pragma unroll
    for (int j = 0; j < 8; j++) cj[j] = cls[grp * 8 + j];

    // 8 independent positions: 21 b64 broadcast + 42 FMA + triangular
    int nvalid = (Ln - base < 64) ? (Ln - base) : 64;
#pragma unroll
    for (int t = 0; t < 8; t++) {
        int i = grp * 8 + t;
        if (i < nvalid) {
            int ci = cj[t];
            float sv = sT[t];
            float accA = (((ci != 0) ? 1.f : 0.f) - Q[ci * 22].y) * sv;
            float accB = 0.f;
#pragma unroll
            for (int k = 0; k < 21; k++) {
                float2 w = Q[ci * 21 + k];       // broadcast ds_read_b64
                accA = fmaf(w.x, msW[k], accA);
                accB = fmaf(w.y, Tc[k], accB);
            }
#pragma unroll
            for (int j = 0; j < 8; j++)          // triangular j < t (static unroll)
                if (j < t) accA = fmaf(Q[ci * 21 + cj[j]].x, sT[j], accA);
            fused[((size_t)b * Ln + base + i) * Cn + lane] = accA + accB;
        }
    }
}

extern "C" void kernel_launch(void* const* d_in, const int* in_sizes, int n_in,
                              void* d_out, int out_size, void* d_ws, size_t ws_size,
                              hipStream_t stream) {
    const float* cls_pred = (const float*)d_in[0];
    const float* source = (const float*)d_in[1];
    const float* cls_r_prob = (const float*)d_in[2];

    float* fused = (float*)d_out;
    float* src_out = fused + (size_t)Bn * Ln * Cn;

    char* w = (char*)d_ws;
    int* cls_idx = (int*)w;                                    // 92416 B
    size_t off = ((size_t)Bn * Ln * 4 + 1023) & ~(size_t)1023;
    float* bs = (float*)(w + off);                             // 16*23*1344*4 = 1.98 MB

    hipLaunchKernelGGL(kB, dim3(Bn * NBn), dim3(256), 0, stream,
                       cls_pred, source, cls_idx, src_out, bs);
    hipLaunchKernelGGL(kC, dim3(Bn * NBn), dim3(512), 0, stream,
                       src_out, cls_idx, cls_r_prob, bs, fused);
}